// Round 4
// baseline (421.834 us; speedup 1.0000x reference)
//
#include <hip/hip_runtime.h>

#define N_NODES 8192
#define D_IN    128
#define D_OUT   64
#define NSPLIT  8

typedef __attribute__((ext_vector_type(8))) short short8;
typedef __attribute__((ext_vector_type(4))) float f32x4;

// fp32 -> bf16 bits, round-to-nearest-even
__device__ __forceinline__ short f2bf(float f) {
    unsigned u = __builtin_bit_cast(unsigned, f);
    u += 0x7fff + ((u >> 16) & 1);
    return (short)(u >> 16);
}

// ================= Kernel 1: deg + bf16 pack of A (single fp32 pass) ========
// Ap unit index ((ri*256 + kt)*64 + quad*16 + r) holds row (ri*16+r),
// k = kt*32 + quad*8 + j (j=0..7), 16 B per unit (MFMA A-frag order).
__global__ __launch_bounds__(256) void k_degpack(const float* __restrict__ A,
                                                 float* __restrict__ deg,
                                                 unsigned short* __restrict__ Ap) {
    const int tid = threadIdx.x;
    const int r = tid >> 4, c = tid & 15;
    const int ri = blockIdx.x;                    // row-tile 0..511
    const int row = ri * 16 + r;
    const f32x4* Ar = (const f32x4*)(A + (size_t)row * N_NODES + c * 8);
    short8* Apv = (short8*)Ap;
    const size_t ubase = ((size_t)ri * 256 + (c >> 2)) * 64 + (c & 3) * 16 + r;

    float s = 0.f;
    f32x4 a0 = __builtin_nontemporal_load(Ar);
    f32x4 a1 = __builtin_nontemporal_load(Ar + 1);
#pragma unroll 4
    for (int m = 0; m < 64; ++m) {
        f32x4 b0, b1;
        if (m < 63) {
            b0 = __builtin_nontemporal_load(Ar + (m + 1) * 32);
            b1 = __builtin_nontemporal_load(Ar + (m + 1) * 32 + 1);
        }
        s += (a0[0] + a0[1]) + (a0[2] + a0[3]) + (a1[0] + a1[1]) + (a1[2] + a1[3]);
        short8 p;
        p[0] = f2bf(a0[0]); p[1] = f2bf(a0[1]); p[2] = f2bf(a0[2]); p[3] = f2bf(a0[3]);
        p[4] = f2bf(a1[0]); p[5] = f2bf(a1[1]); p[6] = f2bf(a1[2]); p[7] = f2bf(a1[3]);
        Apv[ubase + (size_t)m * 256] = p;
        a0 = b0; a1 = b1;
    }
#pragma unroll
    for (int off = 1; off < 16; off <<= 1) s += __shfl_xor(s, off, 64);
    if (c == 0) deg[row] = s;
}

// ================= Kernel 2: G = (diag(rsqrt(deg)) * X) @ W, B-frag packed ==
__global__ __launch_bounds__(256) void k_gpack(const float* __restrict__ X,
                                               const float* __restrict__ W,
                                               const float* __restrict__ deg,
                                               unsigned short* __restrict__ Gp) {
    __shared__ float Wl[D_IN * D_OUT];     // 32 KB
    __shared__ float Xl[32 * 129];         // padded stride 129
    const int t = blockIdx.x, tid = threadIdx.x;

    const float4* W4 = (const float4*)W;
    float4* Wl4 = (float4*)Wl;
#pragma unroll
    for (int i = 0; i < 8; ++i) Wl4[tid + 256 * i] = W4[tid + 256 * i];
    const float4* X4 = (const float4*)(X + (size_t)t * 32 * D_IN);
#pragma unroll
    for (int i = 0; i < 4; ++i) {
        int idx = tid + 256 * i;
        float4 v = X4[idx];
        int r = idx >> 5, c = (idx & 31) * 4;
        float* dst = Xl + r * 129 + c;
        dst[0] = v.x; dst[1] = v.y; dst[2] = v.z; dst[3] = v.w;
    }
    __syncthreads();

    const int kl = tid & 31;
    const int nb = (tid >> 5) * 8;
    float acc[8] = {0.f, 0.f, 0.f, 0.f, 0.f, 0.f, 0.f, 0.f};
    const float* xr = Xl + kl * 129;
    for (int d = 0; d < D_IN; ++d) {
        float xv = xr[d];
        const float* wr = Wl + d * D_OUT + nb;
#pragma unroll
        for (int c = 0; c < 8; ++c) acc[c] += xv * wr[c];
    }
    const float scale = rsqrtf(deg[t * 32 + kl]);
    const int quad = kl >> 3, j = kl & 7;
#pragma unroll
    for (int c = 0; c < 8; ++c) {
        int n = nb + c;
        int u = n >> 4;
        int lanei = quad * 16 + (n & 15);
        Gp[(((size_t)t * 4 + u) * 64 + lanei) * 8 + j] = (unsigned short)f2bf(acc[c] * scale);
    }
}

// ================= Kernel 3 (fused): out = relu(diag(rsqrt(deg)) * (Ap@G)) ==
// 512 blocks x 256 thr. Block = 16 output rows; wave w covers kt in
// [w*64, w*64+64). Cross-wave reduce in LDS, then scale+relu+store.
__global__ __launch_bounds__(256) void k_spmm_fused(const unsigned short* __restrict__ Ap,
                                                    const unsigned short* __restrict__ Gp,
                                                    const float* __restrict__ deg,
                                                    float* __restrict__ out) {
    __shared__ f32x4 lds[256 * 4];               // 16 KB: [wave*64+lane][u]
    const int lane = threadIdx.x & 63;
    const int wave = threadIdx.x >> 6;
    const int quad = lane >> 4;
    const int l15  = lane & 15;
    const int ri   = blockIdx.x;                 // row-tile (16 rows)
    const int kt0  = wave * 64;                  // 64 ktiles per wave

    const short8* Af = (const short8*)Ap + ((size_t)ri * 256 + kt0) * 64 + lane;
    const short8* Gq = (const short8*)Gp + (size_t)kt0 * 256 + lane;

    f32x4 acc[4] = {};
#pragma unroll 4
    for (int i = 0; i < 64; ++i) {
        short8 af = Af[i * 64];
        const short8* gb = Gq + i * 256;
#pragma unroll
        for (int u = 0; u < 4; ++u) {
            acc[u] = __builtin_amdgcn_mfma_f32_16x16x32_bf16(af, gb[u * 64], acc[u], 0, 0, 0);
        }
    }
#pragma unroll
    for (int u = 0; u < 4; ++u) lds[(wave * 64 + lane) * 4 + u] = acc[u];
    __syncthreads();

    // wave w reduces output-column block u = w
    f32x4 v = lds[lane * 4 + wave];
#pragma unroll
    for (int wp = 1; wp < 4; ++wp) v += lds[(wp * 64 + lane) * 4 + wave];

    const f32x4 d4 = *(const f32x4*)(deg + ri * 16 + quad * 4);
#pragma unroll
    for (int r = 0; r < 4; ++r) {
        const float sc = rsqrtf(d4[r]);
        out[(size_t)(ri * 16 + quad * 4 + r) * D_OUT + wave * 16 + l15] =
            fmaxf(v[r] * sc, 0.f);
    }
}

// ================= OLD PATH (fallback if workspace too small) ===============
__global__ __launch_bounds__(256) void k_deg(const float* __restrict__ A,
                                             float* __restrict__ deg) {
    const int wave = threadIdx.x >> 6;
    const int lane = threadIdx.x & 63;
    const int row  = blockIdx.x * 4 + wave;
    const float4* Ar = (const float4*)(A + (size_t)row * N_NODES);
    float s = 0.f;
#pragma unroll
    for (int i = 0; i < 32; ++i) {
        float4 v = Ar[lane + 64 * i];
        s += (v.x + v.y) + (v.z + v.w);
    }
#pragma unroll
    for (int off = 32; off; off >>= 1) s += __shfl_down(s, off, 64);
    if (lane == 0) deg[row] = s;
}

__global__ __launch_bounds__(256) void k_spmm_f32(const float* __restrict__ A,
                                                  const unsigned short* __restrict__ Gp,
                                                  float* __restrict__ h2s) {
    const int lane = threadIdx.x & 63;
    const int wave = threadIdx.x >> 6;
    const int quad = lane >> 4;
    const int l15  = lane & 15;
    const int row  = blockIdx.x * 64 + wave * 16 + l15;
    const float* Ar = A + (size_t)row * N_NODES;
    const int kt0 = blockIdx.y * 32;

    f32x4 acc[4] = {};
    const short8* Gq = (const short8*)Gp;

    for (int kt = kt0; kt < kt0 + 32; ++kt) {
        const float4* pa = (const float4*)(Ar + kt * 32 + quad * 8);
        float4 a0 = pa[0], a1 = pa[1];
        short8 af;
        af[0] = f2bf(a0.x); af[1] = f2bf(a0.y); af[2] = f2bf(a0.z); af[3] = f2bf(a0.w);
        af[4] = f2bf(a1.x); af[5] = f2bf(a1.y); af[6] = f2bf(a1.z); af[7] = f2bf(a1.w);
        const short8* gb = Gq + (size_t)kt * 4 * 64 + lane;
#pragma unroll
        for (int u = 0; u < 4; ++u) {
            acc[u] = __builtin_amdgcn_mfma_f32_16x16x32_bf16(af, gb[u * 64], acc[u], 0, 0, 0);
        }
    }
    float* H = h2s + (size_t)blockIdx.y * ((size_t)N_NODES * D_OUT);
    const int r0 = blockIdx.x * 64 + wave * 16 + quad * 4;
#pragma unroll
    for (int u = 0; u < 4; ++u)
#pragma unroll
        for (int r = 0; r < 4; ++r)
            H[(size_t)(r0 + r) * D_OUT + u * 16 + l15] = acc[u][r];
}

__global__ __launch_bounds__(256) void k_out(const float* __restrict__ h2s,
                                             const float* __restrict__ deg,
                                             float* __restrict__ out) {
    const int idx = blockIdx.x * 256 + threadIdx.x;
    const f32x4* H = (const f32x4*)h2s;
    const int slice = N_NODES * D_OUT / 4;
    f32x4 s = H[idx];
#pragma unroll
    for (int p = 1; p < NSPLIT; ++p) s += H[idx + (size_t)p * slice];
    const float sc = rsqrtf(deg[idx >> 4]);
    f32x4 o;
#pragma unroll
    for (int c = 0; c < 4; ++c) o[c] = fmaxf(s[c] * sc, 0.f);
    ((f32x4*)out)[idx] = o;
}

extern "C" void kernel_launch(void* const* d_in, const int* in_sizes, int n_in,
                              void* d_out, int out_size, void* d_ws, size_t ws_size,
                              hipStream_t stream) {
    const float* X = (const float*)d_in[0];   // features [8192,128]
    const float* A = (const float*)d_in[1];   // adjacency [8192,8192]
    const float* W = (const float*)d_in[2];   // weight [128,64]
    float* out = (float*)d_out;

    char* ws = (char*)d_ws;
    float*          deg = (float*)ws;                                  // 32 KB
    unsigned short* Gp  = (unsigned short*)(ws + 32768);               // 1 MB
    unsigned short* Ap  = (unsigned short*)(ws + 32768 + 1048576);     // 128 MB
    float*          h2s = (float*)(ws + 32768 + 1048576);              // 16 MB (fallback only)

    const size_t need_fused = 32768 + 1048576 + (size_t)N_NODES * N_NODES * 2;

    if (ws_size >= need_fused) {
        k_degpack   <<<N_NODES / 16, 256, 0, stream>>>(A, deg, Ap);
        k_gpack     <<<N_NODES / 32, 256, 0, stream>>>(X, W, deg, Gp);
        k_spmm_fused<<<N_NODES / 16, 256, 0, stream>>>(Ap, Gp, deg, out);
    } else {
        k_deg     <<<N_NODES / 4, 256, 0, stream>>>(A, deg);
        k_gpack   <<<N_NODES / 32, 256, 0, stream>>>(X, W, deg, Gp);
        k_spmm_f32<<<dim3(N_NODES / 64, NSPLIT), 256, 0, stream>>>(A, Gp, h2s);
        k_out     <<<(N_NODES * D_OUT / 4) / 256, 256, 0, stream>>>(h2s, deg, out);
    }
}